// Round 17
// baseline (1425.542 us; speedup 1.0000x reference)
//
#include <hip/hip_runtime.h>

// Problem constants
#define PP 50
#define MM 512
#define NN 1024

// ---------------- workspace layout (float offsets) ----------------
constexpr size_t F_ATB   = 0;                    // [B][P][N] 409600
constexpr size_t F_ATAY  = F_ATB   + 409600;
constexpr size_t F_Y     = F_ATAY  + 409600;
constexpr size_t F_U     = F_Y     + 409600;
constexpr size_t F_DELTA = F_U     + 409600;
constexpr size_t F_BT    = F_DELTA + 409600;     // bt [P*M][8] 204800
constexpr size_t F_AYT   = F_BT    + 204800;     // (spare) 204800
constexpr size_t F_ZA    = F_AYT   + 204800;     // zA [448][1024] gather scratch
constexpr size_t F_ZB    = F_ZA    + 458752;     // zB [448][1024] gathered Atb (persistent)
constexpr size_t F_X0    = F_ZB    + 458752;     // [400][1024]
constexpr size_t F_X1    = F_X0    + 409600;
constexpr size_t F_CODET = F_X1    + 409600;     // [P*1024][8]
constexpr size_t F_PART  = F_CODET + 409600;     // atay partials / encoder partials / decoder dpart (4.2M)
constexpr size_t F_DPART2= F_PART  + 4194304;    // 4*8*1024
constexpr size_t F_H1    = F_DPART2+ 32768;      // h1t [1024][8]
constexpr size_t F_H2    = F_H1    + 8192;       // h2t [512][8]
constexpr size_t F_H3    = F_H2    + 4096;       // h3t [256][8]
constexpr size_t F_HYP   = F_H3    + 2048;       // [B][4]
constexpr size_t F_GCCO  = F_HYP   + 64;         // gccoef 450
constexpr size_t F_SUMNB = F_GCCO  + 512;        // 50
constexpr size_t F_W1B   = F_SUMNB + 64;         // w1b [400][256] (setup)
constexpr size_t F_END   = F_W1B   + 102400;
// int region at F_END: gcoff[0..63], gcsrc[64..575], nbroff[576..639], nbridx[640..1471]

__device__ __forceinline__ float lrelu(float v) { return v >= 0.f ? v : 0.01f * v; }

__device__ __forceinline__ void bred2(float& s1, float& s2, float* sm) {
  #pragma unroll
  for (int off = 32; off > 0; off >>= 1) {
    s1 += __shfl_down(s1, off);
    s2 += __shfl_down(s2, off);
  }
  int w = threadIdx.x >> 6, l = threadIdx.x & 63;
  if (l == 0) { sm[w] = s1; sm[4 + w] = s2; }
  __syncthreads();
  s1 = sm[0] + sm[1] + sm[2] + sm[3];
  s2 = sm[4] + sm[5] + sm[6] + sm[7];
}

// ---------------- setup: graph CSR, coef, degrees (deterministic) ----------------
__global__ __launch_bounds__(512) void ksetup(const int* __restrict__ ei, float* sumnb,
                                              float* gccoef, int* gcoff, int* gcsrc,
                                              int* nbroff, int* nbridx) {
  __shared__ int cin[PP];
  __shared__ int cou[PP];
  __shared__ float sdinv[PP];
  __shared__ int goff[PP + 1], noff[PP + 1];
  int t = threadIdx.x;
  const int* src = ei;
  const int* dst = ei + 400;
  if (t < PP) { cin[t] = 0; cou[t] = 0; }
  __syncthreads();
  if (t < 400) {
    atomicAdd(&cou[src[t]], 1);
    atomicAdd(&cin[dst[t]], 1);
  }
  __syncthreads();
  if (t < PP) {
    sdinv[t] = rsqrtf((float)(cin[t] + 1));
    sumnb[t] = (float)cou[t];
  }
  __syncthreads();
  if (t == 0) {
    goff[0] = 0; noff[0] = 0;
    for (int p = 0; p < PP; ++p) {
      goff[p + 1] = goff[p] + cin[p] + 1;
      noff[p + 1] = noff[p] + cin[p] + cou[p];
    }
  }
  __syncthreads();
  if (t <= PP) { gcoff[t] = goff[t]; nbroff[t] = noff[t]; }
  if (t < 400) {
    int d = dst[t], s = src[t];
    int slot = 0;
    for (int e = 0; e < t; ++e) slot += (dst[e] == d) ? 1 : 0;
    int pos = goff[d] + slot;
    gcsrc[pos] = s;
    gccoef[pos] = sdinv[s] * sdinv[d];
  }
  if (t < PP) {
    int pos = goff[t] + cin[t];
    gcsrc[pos] = t;
    gccoef[pos] = sdinv[t] * sdinv[t];
  }
  if (t < 400) {
    int s = src[t], d = dst[t];
    int so = 0, si = 0;
    for (int e = 0; e < t; ++e) {
      so += (src[e] == s) ? 1 : 0;
      si += (dst[e] == d) ? 1 : 0;
    }
    nbridx[noff[s] + so] = d;
    nbridx[noff[d] + cou[d] + si] = s;
  }
}

// transpose b [B][P][M] -> bt [P*M][B]
__global__ __launch_bounds__(256) void kbt(const float* __restrict__ b, float* __restrict__ bt) {
  int i = blockIdx.x * 256 + threadIdx.x;  // < 204800
  int bb = i / (PP * MM);
  int r = i - bb * (PP * MM);
  bt[r * 8 + bb] = b[i];
}

// A^T q: out[b][p][n] = sum_m A[p][m][n] * q[(p*M+m)*8+b]  (setup only: Atb)
__global__ __launch_bounds__(256) void katz(const float* __restrict__ A, const float* __restrict__ q,
                                            float* __restrict__ outv) {
  __shared__ float red[4][64][8];
  int nb = blockIdx.x, p = blockIdx.y, t = threadIdx.x;
  int ln = t & 63, mg = t >> 6;
  int n = nb * 64 + ln;
  float acc[8] = {0, 0, 0, 0, 0, 0, 0, 0};
  const float* ap = A + ((size_t)p * MM + mg * 128) * NN + n;
  const float* qp = q + ((size_t)p * MM + mg * 128) * 8;
  for (int m0 = 0; m0 < 128; m0 += 8) {
    float av[8];
    #pragma unroll
    for (int u = 0; u < 8; ++u) av[u] = ap[(size_t)(m0 + u) * NN];
    #pragma unroll
    for (int u = 0; u < 8; ++u) {
      #pragma unroll
      for (int bb = 0; bb < 8; ++bb) acc[bb] += av[u] * qp[(m0 + u) * 8 + bb];
    }
  }
  #pragma unroll
  for (int bb = 0; bb < 8; ++bb) red[mg][ln][bb] = acc[bb];
  __syncthreads();
  if (mg == 0) {
    #pragma unroll
    for (int bb = 0; bb < 8; ++bb) {
      float v = red[0][ln][bb] + red[1][ln][bb] + red[2][ln][bb] + red[3][ln][bb];
      outv[((size_t)bb * PP + p) * NN + n] = v;
    }
  }
}

// fused A^T(A y), one HBM read of A. grid (8 mg, 50 p), 256 threads.
__global__ __launch_bounds__(256) void katay2(const float* __restrict__ A,
                                              const float* __restrict__ y,
                                              float* __restrict__ part) {
  __shared__ __align__(16) float sy[8][NN];
  __shared__ float ss[16][8];
  int mg = blockIdx.x, p = blockIdx.y, t = threadIdx.x;
  int w = t >> 6, l = t & 63;
  for (int idx = t; idx < 8 * NN; idx += 256) {
    int bb = idx >> 10, n = idx & 1023;
    sy[bb][n] = y[((size_t)bb * PP + p) * NN + n];
  }
  int nco = w * 256 + 4 * l;
  float4 acc[8];
  #pragma unroll
  for (int b = 0; b < 8; ++b) acc[b] = make_float4(0.f, 0.f, 0.f, 0.f);
  const float* Ab = A + ((size_t)p * MM + (size_t)mg * 64) * NN;
  __syncthreads();
  for (int ch = 0; ch < 4; ++ch) {
    int mbase = ch * 16;
    #pragma unroll
    for (int i = 0; i < 4; i += 2) {
      int r0 = w * 4 + i;
      const float* a0p = Ab + (size_t)(mbase + r0) * NN;
      const float* a1p = a0p + NN;
      float acc0[8] = {0, 0, 0, 0, 0, 0, 0, 0};
      float acc1[8] = {0, 0, 0, 0, 0, 0, 0, 0};
      #pragma unroll
      for (int jj = 0; jj < 4; ++jj) {
        int n0 = 4 * l + 256 * jj;
        float4 a0 = *(const float4*)(a0p + n0);
        float4 a1 = *(const float4*)(a1p + n0);
        #pragma unroll
        for (int bb = 0; bb < 8; ++bb) {
          float4 yv = *(const float4*)&sy[bb][n0];
          acc0[bb] += a0.x * yv.x + a0.y * yv.y + a0.z * yv.z + a0.w * yv.w;
          acc1[bb] += a1.x * yv.x + a1.y * yv.y + a1.z * yv.z + a1.w * yv.w;
        }
      }
      #pragma unroll
      for (int off = 32; off > 0; off >>= 1) {
        #pragma unroll
        for (int bb = 0; bb < 8; ++bb) {
          acc0[bb] += __shfl_down(acc0[bb], off);
          acc1[bb] += __shfl_down(acc1[bb], off);
        }
      }
      if (l == 0) {
        #pragma unroll
        for (int bb = 0; bb < 8; ++bb) {
          ss[r0][bb] = acc0[bb];
          ss[r0 + 1][bb] = acc1[bb];
        }
      }
    }
    __syncthreads();
    #pragma unroll
    for (int m = 0; m < 16; ++m) {
      float4 av = *(const float4*)(Ab + (size_t)(mbase + m) * NN + nco);
      #pragma unroll
      for (int bb = 0; bb < 8; ++bb) {
        float s = ss[m][bb];
        acc[bb].x += s * av.x;
        acc[bb].y += s * av.y;
        acc[bb].z += s * av.z;
        acc[bb].w += s * av.w;
      }
    }
    __syncthreads();
  }
  size_t base = (size_t)mg * 409600;
  #pragma unroll
  for (int bb = 0; bb < 8; ++bb)
    *(float4*)&part[base + (((size_t)bb * PP + p) << 10) + nco] = acc[bb];
}

// reduce 8 mg partials -> atay
__global__ __launch_bounds__(256) void kredAtay8(const float* __restrict__ part,
                                                 float* __restrict__ atay) {
  int i = blockIdx.x * 256 + threadIdx.x;  // < 409600
  float v = 0.f;
  #pragma unroll
  for (int mg = 0; mg < 8; ++mg) v += part[(size_t)mg * 409600 + i];
  atay[i] = v;
}

// generic gather: z[r][c] = sum_nbr coef * x[(b,nbr)][c]; grid (448, Cin/256); pad rows zero
__global__ __launch_bounds__(256) void kgatherX(const float* __restrict__ x, float* __restrict__ z,
                                                int Cin, const int* __restrict__ gcoff,
                                                const int* __restrict__ gcsrc,
                                                const float* __restrict__ gccoef) {
  int r = blockIdx.x, cc = blockIdx.y, t = threadIdx.x;
  int c = cc * 256 + t;
  size_t zi = (size_t)r * Cin + c;
  if (r >= 400) { z[zi] = 0.f; return; }
  int b = r / 50, p = r - b * 50;
  float acc = 0.f;
  int o0 = gcoff[p], o1 = gcoff[p + 1];
  for (int idx = o0; idx < o1; ++idx)
    acc += gccoef[idx] * x[((size_t)b * 50 + gcsrc[idx]) * Cin + c];
  z[zi] = acc;
}

// split-K GEMM 64x64 tile (proven): part[s][r][C] = X[r, slice] @ W[slice, :]
__global__ __launch_bounds__(256) void kgemm(const float* __restrict__ X, const float* __restrict__ W,
                                             float* __restrict__ part, int K, int C, int krange) {
  int cb = blockIdx.x, rb = blockIdx.y, s = blockIdx.z;
  int t = threadIdx.x;
  __shared__ __align__(16) float As[16][64];
  __shared__ __align__(16) float Bs[16][68];
  int rbase = rb * 64, cbase = cb * 64;
  int k0 = s * krange, kend = k0 + krange;
  float acc[4][4] = {};
  int tx = t & 15, ty = t >> 4;
  int lrow = t >> 2, lk = (t & 3) * 4;
  int brow = t >> 4, bc = (t & 15) * 4;
  for (int k = k0; k < kend; k += 16) {
    float4 av = *(const float4*)(X + (size_t)(rbase + lrow) * K + k + lk);
    As[lk + 0][lrow] = av.x;
    As[lk + 1][lrow] = av.y;
    As[lk + 2][lrow] = av.z;
    As[lk + 3][lrow] = av.w;
    *(float4*)&Bs[brow][bc] = *(const float4*)(W + (size_t)(k + brow) * C + cbase + bc);
    __syncthreads();
    #pragma unroll
    for (int kk = 0; kk < 16; ++kk) {
      float4 a = *(const float4*)&As[kk][ty * 4];
      float4 b = *(const float4*)&Bs[kk][tx * 4];
      float aa[4] = {a.x, a.y, a.z, a.w};
      float bb[4] = {b.x, b.y, b.z, b.w};
      #pragma unroll
      for (int i = 0; i < 4; ++i)
        #pragma unroll
        for (int j = 0; j < 4; ++j) acc[i][j] += aa[i] * bb[j];
    }
    __syncthreads();
  }
  #pragma unroll
  for (int i = 0; i < 4; ++i) {
    int r = rbase + ty * 4 + i;
    *(float4*)&part[((size_t)s * 448 + r) * C + cbase + tx * 4] =
        make_float4(acc[i][0], acc[i][1], acc[i][2], acc[i][3]);
  }
}

// split-K GEMM 64x128 tile, 4x8 acc/thread (round-4 inner loop, isolated): C multiple of 128
__global__ __launch_bounds__(256) void kgemm2(const float* __restrict__ X, const float* __restrict__ W,
                                              float* __restrict__ part, int K, int C, int krange) {
  __shared__ __align__(16) float As[16][64];
  __shared__ __align__(16) float Bs[16][132];
  int cb = blockIdx.x, rb = blockIdx.y, s = blockIdx.z;
  int t = threadIdx.x;
  int rbase = rb * 64, cbase = cb * 128;
  int tx = t & 15, ty = t >> 4;
  int lrow = t >> 2, lk = (t & 3) * 4;
  int brow = t >> 4, bc = (t & 15) * 8;
  int k0 = s * krange;
  float acc[4][8];
  #pragma unroll
  for (int i = 0; i < 4; ++i)
    #pragma unroll
    for (int j = 0; j < 8; ++j) acc[i][j] = 0.f;
  for (int kt = k0; kt < k0 + krange; kt += 16) {
    float4 av = *(const float4*)(X + (size_t)(rbase + lrow) * K + kt + lk);
    As[lk + 0][lrow] = av.x;
    As[lk + 1][lrow] = av.y;
    As[lk + 2][lrow] = av.z;
    As[lk + 3][lrow] = av.w;
    const float* wp = W + (size_t)(kt + brow) * C + cbase + bc;
    *(float4*)&Bs[brow][bc] = *(const float4*)wp;
    *(float4*)&Bs[brow][bc + 4] = *(const float4*)(wp + 4);
    __syncthreads();
    #pragma unroll
    for (int kk = 0; kk < 16; ++kk) {
      float4 a = *(const float4*)&As[kk][ty * 4];
      float4 b0 = *(const float4*)&Bs[kk][tx * 4];
      float4 b1 = *(const float4*)&Bs[kk][64 + tx * 4];
      float ar[4] = {a.x, a.y, a.z, a.w};
      float bv[8] = {b0.x, b0.y, b0.z, b0.w, b1.x, b1.y, b1.z, b1.w};
      #pragma unroll
      for (int i = 0; i < 4; ++i)
        #pragma unroll
        for (int j = 0; j < 8; ++j) acc[i][j] += ar[i] * bv[j];
    }
    __syncthreads();
  }
  #pragma unroll
  for (int i = 0; i < 4; ++i) {
    int r = rbase + ty * 4 + i;
    float* pp = part + ((size_t)s * 448 + r) * C + cbase;
    *(float4*)(pp + tx * 4) = make_float4(acc[i][0], acc[i][1], acc[i][2], acc[i][3]);
    *(float4*)(pp + 64 + tx * 4) = make_float4(acc[i][4], acc[i][5], acc[i][6], acc[i][7]);
  }
}

// L1 concat variant: virtual K=2048 over (XA | XB), row stride 1024 each; koff skips zero half
__global__ __launch_bounds__(256) void kgemmC(const float* __restrict__ XA, const float* __restrict__ XB,
                                              const float* __restrict__ W, float* __restrict__ part,
                                              int C, int krange, int koff) {
  int cb = blockIdx.x, rb = blockIdx.y, s = blockIdx.z;
  int t = threadIdx.x;
  __shared__ __align__(16) float As[16][64];
  __shared__ __align__(16) float Bs[16][68];
  int rbase = rb * 64, cbase = cb * 64;
  int k0 = koff + s * krange, kend = k0 + krange;
  float acc[4][4] = {};
  int tx = t & 15, ty = t >> 4;
  int lrow = t >> 2, lk = (t & 3) * 4;
  int brow = t >> 4, bc = (t & 15) * 4;
  for (int k = k0; k < kend; k += 16) {
    int r = rbase + lrow;
    const float* xp = (k < 1024) ? (XA + (size_t)r * 1024 + k)
                                 : (XB + (size_t)r * 1024 + (k - 1024));
    float4 av = *(const float4*)(xp + lk);
    As[lk + 0][lrow] = av.x;
    As[lk + 1][lrow] = av.y;
    As[lk + 2][lrow] = av.z;
    As[lk + 3][lrow] = av.w;
    *(float4*)&Bs[brow][bc] = *(const float4*)(W + (size_t)(k + brow) * C + cbase + bc);
    __syncthreads();
    #pragma unroll
    for (int kk = 0; kk < 16; ++kk) {
      float4 a = *(const float4*)&As[kk][ty * 4];
      float4 b = *(const float4*)&Bs[kk][tx * 4];
      float aa[4] = {a.x, a.y, a.z, a.w};
      float bb[4] = {b.x, b.y, b.z, b.w};
      #pragma unroll
      for (int i = 0; i < 4; ++i)
        #pragma unroll
        for (int j = 0; j < 4; ++j) acc[i][j] += aa[i] * bb[j];
    }
    __syncthreads();
  }
  #pragma unroll
  for (int i = 0; i < 4; ++i) {
    int r = rbase + ty * 4 + i;
    *(float4*)&part[((size_t)s * 448 + r) * C + cbase + tx * 4] =
        make_float4(acc[i][0], acc[i][1], acc[i][2], acc[i][3]);
  }
}

// reduce 8 slices of L1-zB partials -> w1b (setup only)
__global__ __launch_bounds__(256) void kredBase(const float* __restrict__ part,
                                                float* __restrict__ w1b) {
  int r = blockIdx.x, t = threadIdx.x;
  float acc = 0.f;
  #pragma unroll
  for (int s = 0; s < 8; ++s) acc += part[((size_t)s * 448 + r) * 256 + t];
  w1b[(size_t)r * 256 + t] = acc;
}

// encoder epilogue: reduce split-K partials (+ optional base) + bias + lrelu + bn affine;
// last layer: LN -> codet
template <int NCH, bool LASTLN>
__global__ __launch_bounds__(256) void kredE(const float* __restrict__ part, int S,
                                             const float* __restrict__ bias,
                                             const float* __restrict__ bns,
                                             const float* __restrict__ bnt,
                                             float* __restrict__ xout,
                                             const float* __restrict__ lng,
                                             const float* __restrict__ lnb,
                                             float* __restrict__ codet,
                                             const float* __restrict__ base) {
  __shared__ float smr[8];
  constexpr int C = NCH * 256;
  int r = blockIdx.x, t = threadIdx.x;
  float vals[NCH];
  #pragma unroll
  for (int ch = 0; ch < NCH; ++ch) {
    int c = ch * 256 + t;
    float acc = base ? base[(size_t)r * C + c] : 0.f;
    const float* pp = part + (size_t)r * C + c;
    #pragma unroll 4
    for (int s = 0; s < S; ++s) acc += pp[(size_t)s * 448 * C];
    float v = lrelu(acc + bias[c]);
    vals[ch] = v * bns[c] + bnt[c];
  }
  if (!LASTLN) {
    #pragma unroll
    for (int ch = 0; ch < NCH; ++ch)
      xout[(size_t)r * C + ch * 256 + t] = vals[ch];
  } else {
    float s1 = 0.f, s2 = 0.f;
    #pragma unroll
    for (int ch = 0; ch < NCH; ++ch) { s1 += vals[ch]; s2 += vals[ch] * vals[ch]; }
    bred2(s1, s2, smr);
    float mu = s1 / (float)C;
    float var = s2 / (float)C - mu * mu;
    float rs = rsqrtf(var + 1e-5f);
    int b = r / 50, p = r - b * 50;
    #pragma unroll
    for (int ch = 0; ch < NCH; ++ch) {
      int c = ch * 256 + t;
      codet[((size_t)p * C + c) * 8 + b] = (vals[ch] - mu) * rs * lng[c] + lnb[c];
    }
  }
}

// Wd1 GEMV: 512 slices (krange 100), float4 cols, unroll 4 -> 2 blocks/CU
__global__ __launch_bounds__(256) void kwd1(const float* __restrict__ W,
                                            const float* __restrict__ in_t,
                                            float* __restrict__ dpart) {
  int t = threadIdx.x, s = blockIdx.x;
  int k0 = s * 100;
  float4 acc[8];
  #pragma unroll
  for (int b = 0; b < 8; ++b) acc[b] = make_float4(0.f, 0.f, 0.f, 0.f);
  const float* wp = W + (size_t)k0 * 1024 + 4 * t;
  const float* qp = in_t + (size_t)k0 * 8;
  for (int k = 0; k < 100; k += 4) {
    float4 wv[4], qa[4], qb[4];
    #pragma unroll
    for (int u = 0; u < 4; ++u) {
      wv[u] = *(const float4*)(wp + (size_t)(k + u) * 1024);
      qa[u] = *(const float4*)(qp + (k + u) * 8);
      qb[u] = *(const float4*)(qp + (k + u) * 8 + 4);
    }
    #pragma unroll
    for (int u = 0; u < 4; ++u) {
      float qs[8] = {qa[u].x, qa[u].y, qa[u].z, qa[u].w, qb[u].x, qb[u].y, qb[u].z, qb[u].w};
      #pragma unroll
      for (int b = 0; b < 8; ++b) {
        acc[b].x += wv[u].x * qs[b];
        acc[b].y += wv[u].y * qs[b];
        acc[b].z += wv[u].z * qs[b];
        acc[b].w += wv[u].w * qs[b];
      }
    }
  }
  #pragma unroll
  for (int b = 0; b < 8; ++b)
    *(float4*)&dpart[(size_t)(s * 8 + b) * 1024 + 4 * t] = acc[b];
}

// reduce 512 slices -> 4; grid (4 colblocks, 4 slice-groups, 8 b)
__global__ __launch_bounds__(256) void kredA(const float* __restrict__ dpart,
                                             float* __restrict__ dpart2) {
  int cb = blockIdx.x, sg = blockIdx.y, b = blockIdx.z, t = threadIdx.x;
  int c = cb * 256 + t;
  float acc = 0.f;
  const float* pp = dpart + ((size_t)(sg * 128) * 8 + b) * 1024 + c;
  #pragma unroll 8
  for (int i = 0; i < 128; ++i) acc += pp[(size_t)i * 8 * 1024];
  dpart2[((size_t)sg * 8 + b) * 1024 + c] = acc;
}

// small decoder GEMV (d2/d3): blockDim = C/4
__global__ __launch_bounds__(128) void kwdS(const float* __restrict__ W,
                                            const float* __restrict__ in_t,
                                            float* __restrict__ part, int C, int krange) {
  int t = threadIdx.x, s = blockIdx.x;
  int k0 = s * krange;
  float4 acc[8];
  #pragma unroll
  for (int b = 0; b < 8; ++b) acc[b] = make_float4(0.f, 0.f, 0.f, 0.f);
  const float* wp = W + (size_t)k0 * C + 4 * t;
  const float* qp = in_t + (size_t)k0 * 8;
  for (int k = 0; k < krange; ++k) {
    float4 wv = *(const float4*)(wp + (size_t)k * C);
    float4 qa = *(const float4*)(qp + k * 8);
    float4 qb = *(const float4*)(qp + k * 8 + 4);
    float qs[8] = {qa.x, qa.y, qa.z, qa.w, qb.x, qb.y, qb.z, qb.w};
    #pragma unroll
    for (int b = 0; b < 8; ++b) {
      acc[b].x += wv.x * qs[b];
      acc[b].y += wv.y * qs[b];
      acc[b].z += wv.z * qs[b];
      acc[b].w += wv.w * qs[b];
    }
  }
  #pragma unroll
  for (int b = 0; b < 8; ++b)
    *(float4*)&part[(size_t)(s * 8 + b) * C + 4 * t] = acc[b];
}

// reduce split-K partials + bias -> LayerNorm -> lrelu -> transposed out [c][b]; blockDim == C
__global__ __launch_bounds__(1024) void kred(const float* __restrict__ part, int S, int C,
                                             const float* __restrict__ bias,
                                             const float* __restrict__ g,
                                             const float* __restrict__ be,
                                             float* __restrict__ out_t) {
  __shared__ float sm[32];
  int b = blockIdx.x, t = threadIdx.x;
  float v = bias[t];
  const float* pp = part + (size_t)b * C + t;
  #pragma unroll 4
  for (int s = 0; s < S; ++s) v += pp[(size_t)s * 8 * C];
  float s1 = v, s2 = v * v;
  #pragma unroll
  for (int off = 32; off > 0; off >>= 1) {
    s1 += __shfl_down(s1, off);
    s2 += __shfl_down(s2, off);
  }
  int w = t >> 6, l = t & 63;
  int nw = blockDim.x >> 6;
  if (l == 0) { sm[w] = s1; sm[16 + w] = s2; }
  __syncthreads();
  s1 = 0.f; s2 = 0.f;
  for (int i = 0; i < nw; ++i) { s1 += sm[i]; s2 += sm[16 + i]; }
  float inv = 1.f / (float)C;
  float mu = s1 * inv;
  float var = s2 * inv - mu * mu;
  float rs = rsqrtf(var + 1e-5f);
  float o = lrelu((v - mu) * rs * g[t] + be[t]);
  out_t[t * 8 + b] = o;
}

// final fc: hyp[b][4] = clip(sigmoid(h3 @ Wfc + bfc), 1e-4, 0.99)
__global__ __launch_bounds__(256) void kwfc(const float* __restrict__ Wfc, const float* __restrict__ bfc,
                                            const float* __restrict__ h3t, float* __restrict__ hyp) {
  __shared__ float sd[32][257];
  int t = threadIdx.x;
  float4 w = *(const float4*)(Wfc + t * 4);
  #pragma unroll
  for (int bb = 0; bb < 8; ++bb) {
    float x = h3t[t * 8 + bb];
    sd[bb * 4 + 0][t] = x * w.x;
    sd[bb * 4 + 1][t] = x * w.y;
    sd[bb * 4 + 2][t] = x * w.z;
    sd[bb * 4 + 3][t] = x * w.w;
  }
  __syncthreads();
  if (t < 32) {
    float s = 0.f;
    for (int i = 0; i < 256; ++i) s += sd[t][i];
    s += bfc[t & 3];
    float sig = 1.f / (1.f + expf(-s));
    sig = fminf(fmaxf(sig, 1e-4f), 0.99f);
    hyp[t] = sig;
  }
}

__global__ __launch_bounds__(256) void kyupd(const float* __restrict__ atay, const float* __restrict__ atb,
                                             float* y, const float* __restrict__ U,
                                             const float* __restrict__ delta,
                                             const float* __restrict__ hyp,
                                             const float* __restrict__ sumnb, float* __restrict__ outp,
                                             float mg, float mv, int first) {
  int i = blockIdx.x * 256 + threadIdx.x;  // < 409600
  int bb = i / (PP * NN);
  int rem = i - bb * (PP * NN);
  int p = rem >> 10;
  float alpha = hyp[bb * 4 + 0] * 0.01f;
  float g, yv;
  if (first) {
    yv = 0.f;
    g = -atb[i];
  } else {
    float tau = hyp[bb * 4 + 1];
    float rho = hyp[bb * 4 + 2];
    yv = y[i];
    float sg = (yv > 0.f) ? 1.f : ((yv < 0.f) ? -1.f : 0.f);
    g = atay[i] - atb[i] + sg * tau + U[i] * sumnb[p] + delta[i] * rho;
  }
  g = fminf(fmaxf(g, -mg), mg);
  float yn = yv - alpha * g;
  yn = fminf(fmaxf(yn, -mv), mv);
  y[i] = yn;
  outp[i] = yn;
}

__global__ __launch_bounds__(256) void kdeltaU(const float* __restrict__ y, float* __restrict__ delta,
                                               float* __restrict__ U, const float* __restrict__ hyp,
                                               const int* __restrict__ nbroff,
                                               const int* __restrict__ nbridx, float mv, int first) {
  int t = threadIdx.x;
  int n = blockIdx.x * 256 + t;
  int p = blockIdx.y;
  int bb = blockIdx.z;
  int o0 = nbroff[p], o1 = nbroff[p + 1];
  int base = bb * (PP * NN) + p * NN;
  float d = (float)(o1 - o0) * y[base + n];
  for (int idx = o0; idx < o1; ++idx) {
    int q = nbridx[idx];
    d -= y[bb * (PP * NN) + q * NN + n];
  }
  delta[base + n] = d;
  float eta = hyp[bb * 4 + 3];
  float u0 = first ? 0.f : U[base + n];
  float u = u0 + d * eta;
  U[base + n] = fminf(fmaxf(u, -mv), mv);
}

extern "C" void kernel_launch(void* const* d_in, const int* in_sizes, int n_in,
                              void* d_out, int out_size, void* d_ws, size_t ws_size,
                              hipStream_t stream) {
  const float* A    = (const float*)d_in[0];
  const float* bvec = (const float*)d_in[1];
  const float* W1 = (const float*)d_in[2];
  const float* b1 = (const float*)d_in[3];
  const float* bn1s = (const float*)d_in[4];
  const float* bn1t = (const float*)d_in[5];
  const float* W2 = (const float*)d_in[6];
  const float* b2 = (const float*)d_in[7];
  const float* bn2s = (const float*)d_in[8];
  const float* bn2t = (const float*)d_in[9];
  const float* W3 = (const float*)d_in[10];
  const float* b3 = (const float*)d_in[11];
  const float* bn3s = (const float*)d_in[12];
  const float* bn3t = (const float*)d_in[13];
  const float* W4 = (const float*)d_in[14];
  const float* b4 = (const float*)d_in[15];
  const float* bn4s = (const float*)d_in[16];
  const float* bn4t = (const float*)d_in[17];
  const float* W5 = (const float*)d_in[18];
  const float* b5 = (const float*)d_in[19];
  const float* bn5s = (const float*)d_in[20];
  const float* bn5t = (const float*)d_in[21];
  const float* lng = (const float*)d_in[22];
  const float* lnb = (const float*)d_in[23];
  const float* Wd1 = (const float*)d_in[24];
  const float* bd1 = (const float*)d_in[25];
  const float* lnd1g = (const float*)d_in[26];
  const float* lnd1b = (const float*)d_in[27];
  const float* Wd2 = (const float*)d_in[28];
  const float* bd2 = (const float*)d_in[29];
  const float* lnd2g = (const float*)d_in[30];
  const float* lnd2b = (const float*)d_in[31];
  const float* Wd3 = (const float*)d_in[32];
  const float* bd3 = (const float*)d_in[33];
  const float* lnd3g = (const float*)d_in[34];
  const float* lnd3b = (const float*)d_in[35];
  const float* Wfc = (const float*)d_in[36];
  const float* bfc = (const float*)d_in[37];
  const int* ei = (const int*)d_in[38];

  float* out = (float*)d_out;
  float* wsf = (float*)d_ws;
  float* atb = wsf + F_ATB;
  float* atay = wsf + F_ATAY;
  float* yb = wsf + F_Y;
  float* Ub = wsf + F_U;
  float* db = wsf + F_DELTA;
  float* bt = wsf + F_BT;
  float* zA = wsf + F_ZA;
  float* zB = wsf + F_ZB;
  float* x0 = wsf + F_X0;
  float* x1 = wsf + F_X1;
  float* codet = wsf + F_CODET;
  float* part = wsf + F_PART;
  float* dpart = part;  // decoder partials alias (encoder part free by then)
  float* dpart2 = wsf + F_DPART2;
  float* h1t = wsf + F_H1;
  float* h2t = wsf + F_H2;
  float* h3t = wsf + F_H3;
  float* hyp = wsf + F_HYP;
  float* gccoef = wsf + F_GCCO;
  float* sumnb = wsf + F_SUMNB;
  float* w1b = wsf + F_W1B;
  int* wsi = (int*)(wsf + F_END);
  int* gcoff = wsi;
  int* gcsrc = wsi + 64;
  int* nbroff = wsi + 576;
  int* nbridx = wsi + 640;

  ksetup<<<1, 512, 0, stream>>>(ei, sumnb, gccoef, gcoff, gcsrc, nbroff, nbridx);
  kbt<<<800, 256, 0, stream>>>(bvec, bt);
  katz<<<dim3(16, 50), 256, 0, stream>>>(A, bt, atb);
  // gather(Atb) once -> zB, then precompute w1b = zB @ W1[1024:2048] (constant across iters)
  kgatherX<<<dim3(448, 4), 256, 0, stream>>>(atb, zB, 1024, gcoff, gcsrc, gccoef);
  kgemmC<<<dim3(4, 7, 8), 256, 0, stream>>>(zB, zB, W1, part, 256, 128, 1024);
  kredBase<<<400, 256, 0, stream>>>(part, w1b);

  const float mgs[5] = {100.f, 99.f, 98.f, 97.f, 96.f};
  const float mvs[5] = {200.f, 197.f, 194.f, 191.f, 188.f};

  for (int k = 0; k < 5; ++k) {
    if (k > 0) {
      // fused A^T(A y): one HBM read of A, 8 mg partials -> atay
      katay2<<<dim3(8, 50), 256, 0, stream>>>(A, yb, part);
      kredAtay8<<<1600, 256, 0, stream>>>(part, atay);
    }
    // ---- encoder; L1 = zA @ W1[0:1024] + w1b (zB half precomputed) ----
    if (k == 0) {
      // zA half is exactly zero -> L1 output = w1b directly
      kredE<1, false><<<400, 256, 0, stream>>>(part, 0, b1, bn1s, bn1t, x0,
                                               nullptr, nullptr, nullptr, w1b);
    } else {
      kgatherX<<<dim3(448, 4), 256, 0, stream>>>(atay, zA, 1024, gcoff, gcsrc, gccoef);
      kgemm<<<dim3(4, 7, 8), 256, 0, stream>>>(zA, W1, part, 1024, 256, 128);
      kredE<1, false><<<400, 256, 0, stream>>>(part, 8, b1, bn1s, bn1t, x0,
                                               nullptr, nullptr, nullptr, w1b);
    }
    // L2
    kgatherX<<<dim3(448, 1), 256, 0, stream>>>(x0, zA, 256, gcoff, gcsrc, gccoef);
    kgemm<<<dim3(8, 7, 8), 256, 0, stream>>>(zA, W2, part, 256, 512, 32);
    kredE<2, false><<<400, 256, 0, stream>>>(part, 8, b2, bn2s, bn2t, x1,
                                             nullptr, nullptr, nullptr, nullptr);
    // L3 (64x128 tile)
    kgatherX<<<dim3(448, 2), 256, 0, stream>>>(x1, zA, 512, gcoff, gcsrc, gccoef);
    kgemm2<<<dim3(8, 7, 8), 256, 0, stream>>>(zA, W3, part, 512, 1024, 64);
    kredE<4, false><<<400, 256, 0, stream>>>(part, 8, b3, bn3s, bn3t, x0,
                                             nullptr, nullptr, nullptr, nullptr);
    // L4 (64x128 tile)
    kgatherX<<<dim3(448, 4), 256, 0, stream>>>(x0, zA, 1024, gcoff, gcsrc, gccoef);
    kgemm2<<<dim3(8, 7, 8), 256, 0, stream>>>(zA, W4, part, 1024, 1024, 128);
    kredE<4, false><<<400, 256, 0, stream>>>(part, 8, b4, bn4s, bn4t, x1,
                                             nullptr, nullptr, nullptr, nullptr);
    // L5 (64x128 tile; + LayerNorm -> codet transposed)
    kgatherX<<<dim3(448, 4), 256, 0, stream>>>(x1, zA, 1024, gcoff, gcsrc, gccoef);
    kgemm2<<<dim3(8, 7, 8), 256, 0, stream>>>(zA, W5, part, 1024, 1024, 128);
    kredE<4, true><<<400, 256, 0, stream>>>(part, 8, b5, bn5s, bn5t, nullptr,
                                            lng, lnb, codet, nullptr);
    // ---- decoder ----
    kwd1<<<512, 256, 0, stream>>>(Wd1, codet, dpart);
    kredA<<<dim3(4, 4, 8), 256, 0, stream>>>(dpart, dpart2);
    kred<<<8, 1024, 0, stream>>>(dpart2, 4, 1024, bd1, lnd1g, lnd1b, h1t);
    kwdS<<<64, 128, 0, stream>>>(Wd2, h1t, dpart, 512, 16);
    kred<<<8, 512, 0, stream>>>(dpart, 64, 512, bd2, lnd2g, lnd2b, h2t);
    kwdS<<<32, 64, 0, stream>>>(Wd3, h2t, dpart, 256, 16);
    kred<<<8, 256, 0, stream>>>(dpart, 32, 256, bd3, lnd3g, lnd3b, h3t);
    kwfc<<<1, 256, 0, stream>>>(Wfc, bfc, h3t, hyp);
    // ---- y update + output ----
    kyupd<<<1600, 256, 0, stream>>>(atay, atb, yb, Ub, db, hyp, sumnb,
                                    out + (size_t)k * 409600, mgs[k], mvs[k], k == 0);
    kdeltaU<<<dim3(4, 50, 8), 256, 0, stream>>>(yb, db, Ub, hyp, nbroff, nbridx, mvs[k], k == 0);
  }
}

// Round 18
// 1400.068 us; speedup vs baseline: 1.0182x; 1.0182x over previous
//
#include <hip/hip_runtime.h>

// Problem constants
#define PP 50
#define MM 512
#define NN 1024

// ---------------- workspace layout (float offsets) ----------------
constexpr size_t F_ATB   = 0;                    // [B][P][N] 409600
constexpr size_t F_ATAY  = F_ATB   + 409600;
constexpr size_t F_Y     = F_ATAY  + 409600;
constexpr size_t F_U     = F_Y     + 409600;
constexpr size_t F_DELTA = F_U     + 409600;
constexpr size_t F_BT    = F_DELTA + 409600;     // bt [P*M][8] 204800
constexpr size_t F_AYT   = F_BT    + 204800;     // (spare) 204800
constexpr size_t F_ZA    = F_AYT   + 204800;     // zA [448][1024] gather scratch
constexpr size_t F_ZB    = F_ZA    + 458752;     // zB [448][1024] gathered Atb (persistent)
constexpr size_t F_X0    = F_ZB    + 458752;     // [400][1024]
constexpr size_t F_X1    = F_X0    + 409600;
constexpr size_t F_CODET = F_X1    + 409600;     // [P*1024][8]
constexpr size_t F_PART  = F_CODET + 409600;     // atay partials / encoder partials / decoder dpart (4.2M)
constexpr size_t F_DPART2= F_PART  + 4194304;    // 4*8*1024
constexpr size_t F_H1    = F_DPART2+ 32768;      // h1t [1024][8]
constexpr size_t F_H2    = F_H1    + 8192;       // h2t [512][8]
constexpr size_t F_H3    = F_H2    + 4096;       // h3t [256][8]
constexpr size_t F_HYP   = F_H3    + 2048;       // [B][4]
constexpr size_t F_GCCO  = F_HYP   + 64;         // gccoef 450
constexpr size_t F_SUMNB = F_GCCO  + 512;        // 50
constexpr size_t F_W1B   = F_SUMNB + 64;         // w1b [400][256] (setup)
constexpr size_t F_END   = F_W1B   + 102400;
// int region at F_END: gcoff[0..63], gcsrc[64..575], nbroff[576..639], nbridx[640..1471]

__device__ __forceinline__ float lrelu(float v) { return v >= 0.f ? v : 0.01f * v; }

__device__ __forceinline__ void bred2(float& s1, float& s2, float* sm) {
  #pragma unroll
  for (int off = 32; off > 0; off >>= 1) {
    s1 += __shfl_down(s1, off);
    s2 += __shfl_down(s2, off);
  }
  int w = threadIdx.x >> 6, l = threadIdx.x & 63;
  if (l == 0) { sm[w] = s1; sm[4 + w] = s2; }
  __syncthreads();
  s1 = sm[0] + sm[1] + sm[2] + sm[3];
  s2 = sm[4] + sm[5] + sm[6] + sm[7];
}

// ---------------- setup: graph CSR, coef, degrees (deterministic) ----------------
__global__ __launch_bounds__(512) void ksetup(const int* __restrict__ ei, float* sumnb,
                                              float* gccoef, int* gcoff, int* gcsrc,
                                              int* nbroff, int* nbridx) {
  __shared__ int cin[PP];
  __shared__ int cou[PP];
  __shared__ float sdinv[PP];
  __shared__ int goff[PP + 1], noff[PP + 1];
  int t = threadIdx.x;
  const int* src = ei;
  const int* dst = ei + 400;
  if (t < PP) { cin[t] = 0; cou[t] = 0; }
  __syncthreads();
  if (t < 400) {
    atomicAdd(&cou[src[t]], 1);
    atomicAdd(&cin[dst[t]], 1);
  }
  __syncthreads();
  if (t < PP) {
    sdinv[t] = rsqrtf((float)(cin[t] + 1));
    sumnb[t] = (float)cou[t];
  }
  __syncthreads();
  if (t == 0) {
    goff[0] = 0; noff[0] = 0;
    for (int p = 0; p < PP; ++p) {
      goff[p + 1] = goff[p] + cin[p] + 1;
      noff[p + 1] = noff[p] + cin[p] + cou[p];
    }
  }
  __syncthreads();
  if (t <= PP) { gcoff[t] = goff[t]; nbroff[t] = noff[t]; }
  if (t < 400) {
    int d = dst[t], s = src[t];
    int slot = 0;
    for (int e = 0; e < t; ++e) slot += (dst[e] == d) ? 1 : 0;
    int pos = goff[d] + slot;
    gcsrc[pos] = s;
    gccoef[pos] = sdinv[s] * sdinv[d];
  }
  if (t < PP) {
    int pos = goff[t] + cin[t];
    gcsrc[pos] = t;
    gccoef[pos] = sdinv[t] * sdinv[t];
  }
  if (t < 400) {
    int s = src[t], d = dst[t];
    int so = 0, si = 0;
    for (int e = 0; e < t; ++e) {
      so += (src[e] == s) ? 1 : 0;
      si += (dst[e] == d) ? 1 : 0;
    }
    nbridx[noff[s] + so] = d;
    nbridx[noff[d] + cou[d] + si] = s;
  }
}

// transpose b [B][P][M] -> bt [P*M][B]
__global__ __launch_bounds__(256) void kbt(const float* __restrict__ b, float* __restrict__ bt) {
  int i = blockIdx.x * 256 + threadIdx.x;  // < 204800
  int bb = i / (PP * MM);
  int r = i - bb * (PP * MM);
  bt[r * 8 + bb] = b[i];
}

// A^T q: out[b][p][n] = sum_m A[p][m][n] * q[(p*M+m)*8+b]  (setup only: Atb)
__global__ __launch_bounds__(256) void katz(const float* __restrict__ A, const float* __restrict__ q,
                                            float* __restrict__ outv) {
  __shared__ float red[4][64][8];
  int nb = blockIdx.x, p = blockIdx.y, t = threadIdx.x;
  int ln = t & 63, mg = t >> 6;
  int n = nb * 64 + ln;
  float acc[8] = {0, 0, 0, 0, 0, 0, 0, 0};
  const float* ap = A + ((size_t)p * MM + mg * 128) * NN + n;
  const float* qp = q + ((size_t)p * MM + mg * 128) * 8;
  for (int m0 = 0; m0 < 128; m0 += 8) {
    float av[8];
    #pragma unroll
    for (int u = 0; u < 8; ++u) av[u] = ap[(size_t)(m0 + u) * NN];
    #pragma unroll
    for (int u = 0; u < 8; ++u) {
      #pragma unroll
      for (int bb = 0; bb < 8; ++bb) acc[bb] += av[u] * qp[(m0 + u) * 8 + bb];
    }
  }
  #pragma unroll
  for (int bb = 0; bb < 8; ++bb) red[mg][ln][bb] = acc[bb];
  __syncthreads();
  if (mg == 0) {
    #pragma unroll
    for (int bb = 0; bb < 8; ++bb) {
      float v = red[0][ln][bb] + red[1][ln][bb] + red[2][ln][bb] + red[3][ln][bb];
      outv[((size_t)bb * PP + p) * NN + n] = v;
    }
  }
}

// fused A^T(A y), one HBM read of A. grid (8 mg, 50 p), 256 threads.
__global__ __launch_bounds__(256) void katay2(const float* __restrict__ A,
                                              const float* __restrict__ y,
                                              float* __restrict__ part) {
  __shared__ __align__(16) float sy[8][NN];
  __shared__ float ss[16][8];
  int mg = blockIdx.x, p = blockIdx.y, t = threadIdx.x;
  int w = t >> 6, l = t & 63;
  for (int idx = t; idx < 8 * NN; idx += 256) {
    int bb = idx >> 10, n = idx & 1023;
    sy[bb][n] = y[((size_t)bb * PP + p) * NN + n];
  }
  int nco = w * 256 + 4 * l;
  float4 acc[8];
  #pragma unroll
  for (int b = 0; b < 8; ++b) acc[b] = make_float4(0.f, 0.f, 0.f, 0.f);
  const float* Ab = A + ((size_t)p * MM + (size_t)mg * 64) * NN;
  __syncthreads();
  for (int ch = 0; ch < 4; ++ch) {
    int mbase = ch * 16;
    #pragma unroll
    for (int i = 0; i < 4; i += 2) {
      int r0 = w * 4 + i;
      const float* a0p = Ab + (size_t)(mbase + r0) * NN;
      const float* a1p = a0p + NN;
      float acc0[8] = {0, 0, 0, 0, 0, 0, 0, 0};
      float acc1[8] = {0, 0, 0, 0, 0, 0, 0, 0};
      #pragma unroll
      for (int jj = 0; jj < 4; ++jj) {
        int n0 = 4 * l + 256 * jj;
        float4 a0 = *(const float4*)(a0p + n0);
        float4 a1 = *(const float4*)(a1p + n0);
        #pragma unroll
        for (int bb = 0; bb < 8; ++bb) {
          float4 yv = *(const float4*)&sy[bb][n0];
          acc0[bb] += a0.x * yv.x + a0.y * yv.y + a0.z * yv.z + a0.w * yv.w;
          acc1[bb] += a1.x * yv.x + a1.y * yv.y + a1.z * yv.z + a1.w * yv.w;
        }
      }
      #pragma unroll
      for (int off = 32; off > 0; off >>= 1) {
        #pragma unroll
        for (int bb = 0; bb < 8; ++bb) {
          acc0[bb] += __shfl_down(acc0[bb], off);
          acc1[bb] += __shfl_down(acc1[bb], off);
        }
      }
      if (l == 0) {
        #pragma unroll
        for (int bb = 0; bb < 8; ++bb) {
          ss[r0][bb] = acc0[bb];
          ss[r0 + 1][bb] = acc1[bb];
        }
      }
    }
    __syncthreads();
    #pragma unroll
    for (int m = 0; m < 16; ++m) {
      float4 av = *(const float4*)(Ab + (size_t)(mbase + m) * NN + nco);
      #pragma unroll
      for (int bb = 0; bb < 8; ++bb) {
        float s = ss[m][bb];
        acc[bb].x += s * av.x;
        acc[bb].y += s * av.y;
        acc[bb].z += s * av.z;
        acc[bb].w += s * av.w;
      }
    }
    __syncthreads();
  }
  size_t base = (size_t)mg * 409600;
  #pragma unroll
  for (int bb = 0; bb < 8; ++bb)
    *(float4*)&part[base + (((size_t)bb * PP + p) << 10) + nco] = acc[bb];
}

// reduce 8 mg partials -> atay
__global__ __launch_bounds__(256) void kredAtay8(const float* __restrict__ part,
                                                 float* __restrict__ atay) {
  int i = blockIdx.x * 256 + threadIdx.x;  // < 409600
  float v = 0.f;
  #pragma unroll
  for (int mg = 0; mg < 8; ++mg) v += part[(size_t)mg * 409600 + i];
  atay[i] = v;
}

// generic gather: z[r][c] = sum_nbr coef * x[(b,nbr)][c]; grid (448, Cin/256); pad rows zero
__global__ __launch_bounds__(256) void kgatherX(const float* __restrict__ x, float* __restrict__ z,
                                                int Cin, const int* __restrict__ gcoff,
                                                const int* __restrict__ gcsrc,
                                                const float* __restrict__ gccoef) {
  int r = blockIdx.x, cc = blockIdx.y, t = threadIdx.x;
  int c = cc * 256 + t;
  size_t zi = (size_t)r * Cin + c;
  if (r >= 400) { z[zi] = 0.f; return; }
  int b = r / 50, p = r - b * 50;
  float acc = 0.f;
  int o0 = gcoff[p], o1 = gcoff[p + 1];
  for (int idx = o0; idx < o1; ++idx)
    acc += gccoef[idx] * x[((size_t)b * 50 + gcsrc[idx]) * Cin + c];
  z[zi] = acc;
}

// split-K GEMM 64x64 tile (proven): part[s][r][C] = X[r, slice] @ W[slice, :]
__global__ __launch_bounds__(256) void kgemm(const float* __restrict__ X, const float* __restrict__ W,
                                             float* __restrict__ part, int K, int C, int krange) {
  int cb = blockIdx.x, rb = blockIdx.y, s = blockIdx.z;
  int t = threadIdx.x;
  __shared__ __align__(16) float As[16][64];
  __shared__ __align__(16) float Bs[16][68];
  int rbase = rb * 64, cbase = cb * 64;
  int k0 = s * krange, kend = k0 + krange;
  float acc[4][4] = {};
  int tx = t & 15, ty = t >> 4;
  int lrow = t >> 2, lk = (t & 3) * 4;
  int brow = t >> 4, bc = (t & 15) * 4;
  for (int k = k0; k < kend; k += 16) {
    float4 av = *(const float4*)(X + (size_t)(rbase + lrow) * K + k + lk);
    As[lk + 0][lrow] = av.x;
    As[lk + 1][lrow] = av.y;
    As[lk + 2][lrow] = av.z;
    As[lk + 3][lrow] = av.w;
    *(float4*)&Bs[brow][bc] = *(const float4*)(W + (size_t)(k + brow) * C + cbase + bc);
    __syncthreads();
    #pragma unroll
    for (int kk = 0; kk < 16; ++kk) {
      float4 a = *(const float4*)&As[kk][ty * 4];
      float4 b = *(const float4*)&Bs[kk][tx * 4];
      float aa[4] = {a.x, a.y, a.z, a.w};
      float bb[4] = {b.x, b.y, b.z, b.w};
      #pragma unroll
      for (int i = 0; i < 4; ++i)
        #pragma unroll
        for (int j = 0; j < 4; ++j) acc[i][j] += aa[i] * bb[j];
    }
    __syncthreads();
  }
  #pragma unroll
  for (int i = 0; i < 4; ++i) {
    int r = rbase + ty * 4 + i;
    *(float4*)&part[((size_t)s * 448 + r) * C + cbase + tx * 4] =
        make_float4(acc[i][0], acc[i][1], acc[i][2], acc[i][3]);
  }
}

// L1 concat variant: virtual K=2048 over (XA | XB), row stride 1024 each; koff skips zero half
__global__ __launch_bounds__(256) void kgemmC(const float* __restrict__ XA, const float* __restrict__ XB,
                                              const float* __restrict__ W, float* __restrict__ part,
                                              int C, int krange, int koff) {
  int cb = blockIdx.x, rb = blockIdx.y, s = blockIdx.z;
  int t = threadIdx.x;
  __shared__ __align__(16) float As[16][64];
  __shared__ __align__(16) float Bs[16][68];
  int rbase = rb * 64, cbase = cb * 64;
  int k0 = koff + s * krange, kend = k0 + krange;
  float acc[4][4] = {};
  int tx = t & 15, ty = t >> 4;
  int lrow = t >> 2, lk = (t & 3) * 4;
  int brow = t >> 4, bc = (t & 15) * 4;
  for (int k = k0; k < kend; k += 16) {
    int r = rbase + lrow;
    const float* xp = (k < 1024) ? (XA + (size_t)r * 1024 + k)
                                 : (XB + (size_t)r * 1024 + (k - 1024));
    float4 av = *(const float4*)(xp + lk);
    As[lk + 0][lrow] = av.x;
    As[lk + 1][lrow] = av.y;
    As[lk + 2][lrow] = av.z;
    As[lk + 3][lrow] = av.w;
    *(float4*)&Bs[brow][bc] = *(const float4*)(W + (size_t)(k + brow) * C + cbase + bc);
    __syncthreads();
    #pragma unroll
    for (int kk = 0; kk < 16; ++kk) {
      float4 a = *(const float4*)&As[kk][ty * 4];
      float4 b = *(const float4*)&Bs[kk][tx * 4];
      float aa[4] = {a.x, a.y, a.z, a.w};
      float bb[4] = {b.x, b.y, b.z, b.w};
      #pragma unroll
      for (int i = 0; i < 4; ++i)
        #pragma unroll
        for (int j = 0; j < 4; ++j) acc[i][j] += aa[i] * bb[j];
    }
    __syncthreads();
  }
  #pragma unroll
  for (int i = 0; i < 4; ++i) {
    int r = rbase + ty * 4 + i;
    *(float4*)&part[((size_t)s * 448 + r) * C + cbase + tx * 4] =
        make_float4(acc[i][0], acc[i][1], acc[i][2], acc[i][3]);
  }
}

// reduce 8 slices of L1-zB partials -> w1b (setup only)
__global__ __launch_bounds__(256) void kredBase(const float* __restrict__ part,
                                                float* __restrict__ w1b) {
  int r = blockIdx.x, t = threadIdx.x;
  float acc = 0.f;
  #pragma unroll
  for (int s = 0; s < 8; ++s) acc += part[((size_t)s * 448 + r) * 256 + t];
  w1b[(size_t)r * 256 + t] = acc;
}

// encoder epilogue: reduce split-K partials (+ optional base) + bias + lrelu + bn affine;
// last layer: LN -> codet
template <int NCH, bool LASTLN>
__global__ __launch_bounds__(256) void kredE(const float* __restrict__ part, int S,
                                             const float* __restrict__ bias,
                                             const float* __restrict__ bns,
                                             const float* __restrict__ bnt,
                                             float* __restrict__ xout,
                                             const float* __restrict__ lng,
                                             const float* __restrict__ lnb,
                                             float* __restrict__ codet,
                                             const float* __restrict__ base) {
  __shared__ float smr[8];
  constexpr int C = NCH * 256;
  int r = blockIdx.x, t = threadIdx.x;
  float vals[NCH];
  #pragma unroll
  for (int ch = 0; ch < NCH; ++ch) {
    int c = ch * 256 + t;
    float acc = base ? base[(size_t)r * C + c] : 0.f;
    const float* pp = part + (size_t)r * C + c;
    #pragma unroll 4
    for (int s = 0; s < S; ++s) acc += pp[(size_t)s * 448 * C];
    float v = lrelu(acc + bias[c]);
    vals[ch] = v * bns[c] + bnt[c];
  }
  if (!LASTLN) {
    #pragma unroll
    for (int ch = 0; ch < NCH; ++ch)
      xout[(size_t)r * C + ch * 256 + t] = vals[ch];
  } else {
    float s1 = 0.f, s2 = 0.f;
    #pragma unroll
    for (int ch = 0; ch < NCH; ++ch) { s1 += vals[ch]; s2 += vals[ch] * vals[ch]; }
    bred2(s1, s2, smr);
    float mu = s1 / (float)C;
    float var = s2 / (float)C - mu * mu;
    float rs = rsqrtf(var + 1e-5f);
    int b = r / 50, p = r - b * 50;
    #pragma unroll
    for (int ch = 0; ch < NCH; ++ch) {
      int c = ch * 256 + t;
      codet[((size_t)p * C + c) * 8 + b] = (vals[ch] - mu) * rs * lng[c] + lnb[c];
    }
  }
}

// Wd1 GEMV: 512 slices (krange 100), float4 cols, unroll 4 -> 2 blocks/CU
__global__ __launch_bounds__(256) void kwd1(const float* __restrict__ W,
                                            const float* __restrict__ in_t,
                                            float* __restrict__ dpart) {
  int t = threadIdx.x, s = blockIdx.x;
  int k0 = s * 100;
  float4 acc[8];
  #pragma unroll
  for (int b = 0; b < 8; ++b) acc[b] = make_float4(0.f, 0.f, 0.f, 0.f);
  const float* wp = W + (size_t)k0 * 1024 + 4 * t;
  const float* qp = in_t + (size_t)k0 * 8;
  for (int k = 0; k < 100; k += 4) {
    float4 wv[4], qa[4], qb[4];
    #pragma unroll
    for (int u = 0; u < 4; ++u) {
      wv[u] = *(const float4*)(wp + (size_t)(k + u) * 1024);
      qa[u] = *(const float4*)(qp + (k + u) * 8);
      qb[u] = *(const float4*)(qp + (k + u) * 8 + 4);
    }
    #pragma unroll
    for (int u = 0; u < 4; ++u) {
      float qs[8] = {qa[u].x, qa[u].y, qa[u].z, qa[u].w, qb[u].x, qb[u].y, qb[u].z, qb[u].w};
      #pragma unroll
      for (int b = 0; b < 8; ++b) {
        acc[b].x += wv[u].x * qs[b];
        acc[b].y += wv[u].y * qs[b];
        acc[b].z += wv[u].z * qs[b];
        acc[b].w += wv[u].w * qs[b];
      }
    }
  }
  #pragma unroll
  for (int b = 0; b < 8; ++b)
    *(float4*)&dpart[(size_t)(s * 8 + b) * 1024 + 4 * t] = acc[b];
}

// reduce 512 slices -> 4; grid (4 colblocks, 4 slice-groups, 8 b)
__global__ __launch_bounds__(256) void kredA(const float* __restrict__ dpart,
                                             float* __restrict__ dpart2) {
  int cb = blockIdx.x, sg = blockIdx.y, b = blockIdx.z, t = threadIdx.x;
  int c = cb * 256 + t;
  float acc = 0.f;
  const float* pp = dpart + ((size_t)(sg * 128) * 8 + b) * 1024 + c;
  #pragma unroll 8
  for (int i = 0; i < 128; ++i) acc += pp[(size_t)i * 8 * 1024];
  dpart2[((size_t)sg * 8 + b) * 1024 + c] = acc;
}

// small decoder GEMV (d2/d3): blockDim = C/4
__global__ __launch_bounds__(128) void kwdS(const float* __restrict__ W,
                                            const float* __restrict__ in_t,
                                            float* __restrict__ part, int C, int krange) {
  int t = threadIdx.x, s = blockIdx.x;
  int k0 = s * krange;
  float4 acc[8];
  #pragma unroll
  for (int b = 0; b < 8; ++b) acc[b] = make_float4(0.f, 0.f, 0.f, 0.f);
  const float* wp = W + (size_t)k0 * C + 4 * t;
  const float* qp = in_t + (size_t)k0 * 8;
  for (int k = 0; k < krange; ++k) {
    float4 wv = *(const float4*)(wp + (size_t)k * C);
    float4 qa = *(const float4*)(qp + k * 8);
    float4 qb = *(const float4*)(qp + k * 8 + 4);
    float qs[8] = {qa.x, qa.y, qa.z, qa.w, qb.x, qb.y, qb.z, qb.w};
    #pragma unroll
    for (int b = 0; b < 8; ++b) {
      acc[b].x += wv.x * qs[b];
      acc[b].y += wv.y * qs[b];
      acc[b].z += wv.z * qs[b];
      acc[b].w += wv.w * qs[b];
    }
  }
  #pragma unroll
  for (int b = 0; b < 8; ++b)
    *(float4*)&part[(size_t)(s * 8 + b) * C + 4 * t] = acc[b];
}

// reduce split-K partials + bias -> LayerNorm -> lrelu -> transposed out [c][b]; blockDim == C
__global__ __launch_bounds__(1024) void kred(const float* __restrict__ part, int S, int C,
                                             const float* __restrict__ bias,
                                             const float* __restrict__ g,
                                             const float* __restrict__ be,
                                             float* __restrict__ out_t) {
  __shared__ float sm[32];
  int b = blockIdx.x, t = threadIdx.x;
  float v = bias[t];
  const float* pp = part + (size_t)b * C + t;
  #pragma unroll 4
  for (int s = 0; s < S; ++s) v += pp[(size_t)s * 8 * C];
  float s1 = v, s2 = v * v;
  #pragma unroll
  for (int off = 32; off > 0; off >>= 1) {
    s1 += __shfl_down(s1, off);
    s2 += __shfl_down(s2, off);
  }
  int w = t >> 6, l = t & 63;
  int nw = blockDim.x >> 6;
  if (l == 0) { sm[w] = s1; sm[16 + w] = s2; }
  __syncthreads();
  s1 = 0.f; s2 = 0.f;
  for (int i = 0; i < nw; ++i) { s1 += sm[i]; s2 += sm[16 + i]; }
  float inv = 1.f / (float)C;
  float mu = s1 * inv;
  float var = s2 * inv - mu * mu;
  float rs = rsqrtf(var + 1e-5f);
  float o = lrelu((v - mu) * rs * g[t] + be[t]);
  out_t[t * 8 + b] = o;
}

// final fc: hyp[b][4] = clip(sigmoid(h3 @ Wfc + bfc), 1e-4, 0.99)
__global__ __launch_bounds__(256) void kwfc(const float* __restrict__ Wfc, const float* __restrict__ bfc,
                                            const float* __restrict__ h3t, float* __restrict__ hyp) {
  __shared__ float sd[32][257];
  int t = threadIdx.x;
  float4 w = *(const float4*)(Wfc + t * 4);
  #pragma unroll
  for (int bb = 0; bb < 8; ++bb) {
    float x = h3t[t * 8 + bb];
    sd[bb * 4 + 0][t] = x * w.x;
    sd[bb * 4 + 1][t] = x * w.y;
    sd[bb * 4 + 2][t] = x * w.z;
    sd[bb * 4 + 3][t] = x * w.w;
  }
  __syncthreads();
  if (t < 32) {
    float s = 0.f;
    for (int i = 0; i < 256; ++i) s += sd[t][i];
    s += bfc[t & 3];
    float sig = 1.f / (1.f + expf(-s));
    sig = fminf(fmaxf(sig, 1e-4f), 0.99f);
    hyp[t] = sig;
  }
}

__global__ __launch_bounds__(256) void kyupd(const float* __restrict__ atay, const float* __restrict__ atb,
                                             float* y, const float* __restrict__ U,
                                             const float* __restrict__ delta,
                                             const float* __restrict__ hyp,
                                             const float* __restrict__ sumnb, float* __restrict__ outp,
                                             float mg, float mv, int first) {
  int i = blockIdx.x * 256 + threadIdx.x;  // < 409600
  int bb = i / (PP * NN);
  int rem = i - bb * (PP * NN);
  int p = rem >> 10;
  float alpha = hyp[bb * 4 + 0] * 0.01f;
  float g, yv;
  if (first) {
    yv = 0.f;
    g = -atb[i];
  } else {
    float tau = hyp[bb * 4 + 1];
    float rho = hyp[bb * 4 + 2];
    yv = y[i];
    float sg = (yv > 0.f) ? 1.f : ((yv < 0.f) ? -1.f : 0.f);
    g = atay[i] - atb[i] + sg * tau + U[i] * sumnb[p] + delta[i] * rho;
  }
  g = fminf(fmaxf(g, -mg), mg);
  float yn = yv - alpha * g;
  yn = fminf(fmaxf(yn, -mv), mv);
  y[i] = yn;
  outp[i] = yn;
}

__global__ __launch_bounds__(256) void kdeltaU(const float* __restrict__ y, float* __restrict__ delta,
                                               float* __restrict__ U, const float* __restrict__ hyp,
                                               const int* __restrict__ nbroff,
                                               const int* __restrict__ nbridx, float mv, int first) {
  int t = threadIdx.x;
  int n = blockIdx.x * 256 + t;
  int p = blockIdx.y;
  int bb = blockIdx.z;
  int o0 = nbroff[p], o1 = nbroff[p + 1];
  int base = bb * (PP * NN) + p * NN;
  float d = (float)(o1 - o0) * y[base + n];
  for (int idx = o0; idx < o1; ++idx) {
    int q = nbridx[idx];
    d -= y[bb * (PP * NN) + q * NN + n];
  }
  delta[base + n] = d;
  float eta = hyp[bb * 4 + 3];
  float u0 = first ? 0.f : U[base + n];
  float u = u0 + d * eta;
  U[base + n] = fminf(fmaxf(u, -mv), mv);
}

extern "C" void kernel_launch(void* const* d_in, const int* in_sizes, int n_in,
                              void* d_out, int out_size, void* d_ws, size_t ws_size,
                              hipStream_t stream) {
  const float* A    = (const float*)d_in[0];
  const float* bvec = (const float*)d_in[1];
  const float* W1 = (const float*)d_in[2];
  const float* b1 = (const float*)d_in[3];
  const float* bn1s = (const float*)d_in[4];
  const float* bn1t = (const float*)d_in[5];
  const float* W2 = (const float*)d_in[6];
  const float* b2 = (const float*)d_in[7];
  const float* bn2s = (const float*)d_in[8];
  const float* bn2t = (const float*)d_in[9];
  const float* W3 = (const float*)d_in[10];
  const float* b3 = (const float*)d_in[11];
  const float* bn3s = (const float*)d_in[12];
  const float* bn3t = (const float*)d_in[13];
  const float* W4 = (const float*)d_in[14];
  const float* b4 = (const float*)d_in[15];
  const float* bn4s = (const float*)d_in[16];
  const float* bn4t = (const float*)d_in[17];
  const float* W5 = (const float*)d_in[18];
  const float* b5 = (const float*)d_in[19];
  const float* bn5s = (const float*)d_in[20];
  const float* bn5t = (const float*)d_in[21];
  const float* lng = (const float*)d_in[22];
  const float* lnb = (const float*)d_in[23];
  const float* Wd1 = (const float*)d_in[24];
  const float* bd1 = (const float*)d_in[25];
  const float* lnd1g = (const float*)d_in[26];
  const float* lnd1b = (const float*)d_in[27];
  const float* Wd2 = (const float*)d_in[28];
  const float* bd2 = (const float*)d_in[29];
  const float* lnd2g = (const float*)d_in[30];
  const float* lnd2b = (const float*)d_in[31];
  const float* Wd3 = (const float*)d_in[32];
  const float* bd3 = (const float*)d_in[33];
  const float* lnd3g = (const float*)d_in[34];
  const float* lnd3b = (const float*)d_in[35];
  const float* Wfc = (const float*)d_in[36];
  const float* bfc = (const float*)d_in[37];
  const int* ei = (const int*)d_in[38];

  float* out = (float*)d_out;
  float* wsf = (float*)d_ws;
  float* atb = wsf + F_ATB;
  float* atay = wsf + F_ATAY;
  float* yb = wsf + F_Y;
  float* Ub = wsf + F_U;
  float* db = wsf + F_DELTA;
  float* bt = wsf + F_BT;
  float* zA = wsf + F_ZA;
  float* zB = wsf + F_ZB;
  float* x0 = wsf + F_X0;
  float* x1 = wsf + F_X1;
  float* codet = wsf + F_CODET;
  float* part = wsf + F_PART;
  float* dpart = part;  // decoder partials alias (encoder part free by then)
  float* dpart2 = wsf + F_DPART2;
  float* h1t = wsf + F_H1;
  float* h2t = wsf + F_H2;
  float* h3t = wsf + F_H3;
  float* hyp = wsf + F_HYP;
  float* gccoef = wsf + F_GCCO;
  float* sumnb = wsf + F_SUMNB;
  float* w1b = wsf + F_W1B;
  int* wsi = (int*)(wsf + F_END);
  int* gcoff = wsi;
  int* gcsrc = wsi + 64;
  int* nbroff = wsi + 576;
  int* nbridx = wsi + 640;

  ksetup<<<1, 512, 0, stream>>>(ei, sumnb, gccoef, gcoff, gcsrc, nbroff, nbridx);
  kbt<<<800, 256, 0, stream>>>(bvec, bt);
  katz<<<dim3(16, 50), 256, 0, stream>>>(A, bt, atb);
  // gather(Atb) once -> zB, then precompute w1b = zB @ W1[1024:2048] (constant across iters)
  kgatherX<<<dim3(448, 4), 256, 0, stream>>>(atb, zB, 1024, gcoff, gcsrc, gccoef);
  kgemmC<<<dim3(4, 7, 8), 256, 0, stream>>>(zB, zB, W1, part, 256, 128, 1024);
  kredBase<<<400, 256, 0, stream>>>(part, w1b);

  const float mgs[5] = {100.f, 99.f, 98.f, 97.f, 96.f};
  const float mvs[5] = {200.f, 197.f, 194.f, 191.f, 188.f};

  for (int k = 0; k < 5; ++k) {
    if (k > 0) {
      // fused A^T(A y): one HBM read of A, 8 mg partials -> atay
      katay2<<<dim3(8, 50), 256, 0, stream>>>(A, yb, part);
      kredAtay8<<<1600, 256, 0, stream>>>(part, atay);
    }
    // ---- encoder; L1 = zA @ W1[0:1024] + w1b (zB half precomputed) ----
    if (k == 0) {
      // zA half is exactly zero -> L1 output = w1b directly
      kredE<1, false><<<400, 256, 0, stream>>>(part, 0, b1, bn1s, bn1t, x0,
                                               nullptr, nullptr, nullptr, w1b);
    } else {
      kgatherX<<<dim3(448, 4), 256, 0, stream>>>(atay, zA, 1024, gcoff, gcsrc, gccoef);
      kgemm<<<dim3(4, 7, 8), 256, 0, stream>>>(zA, W1, part, 1024, 256, 128);
      kredE<1, false><<<400, 256, 0, stream>>>(part, 8, b1, bn1s, bn1t, x0,
                                               nullptr, nullptr, nullptr, w1b);
    }
    // L2
    kgatherX<<<dim3(448, 1), 256, 0, stream>>>(x0, zA, 256, gcoff, gcsrc, gccoef);
    kgemm<<<dim3(8, 7, 8), 256, 0, stream>>>(zA, W2, part, 256, 512, 32);
    kredE<2, false><<<400, 256, 0, stream>>>(part, 8, b2, bn2s, bn2t, x1,
                                             nullptr, nullptr, nullptr, nullptr);
    // L3
    kgatherX<<<dim3(448, 2), 256, 0, stream>>>(x1, zA, 512, gcoff, gcsrc, gccoef);
    kgemm<<<dim3(16, 7, 8), 256, 0, stream>>>(zA, W3, part, 512, 1024, 64);
    kredE<4, false><<<400, 256, 0, stream>>>(part, 8, b3, bn3s, bn3t, x0,
                                             nullptr, nullptr, nullptr, nullptr);
    // L4
    kgatherX<<<dim3(448, 4), 256, 0, stream>>>(x0, zA, 1024, gcoff, gcsrc, gccoef);
    kgemm<<<dim3(16, 7, 8), 256, 0, stream>>>(zA, W4, part, 1024, 1024, 128);
    kredE<4, false><<<400, 256, 0, stream>>>(part, 8, b4, bn4s, bn4t, x1,
                                             nullptr, nullptr, nullptr, nullptr);
    // L5 (+ LayerNorm -> codet transposed)
    kgatherX<<<dim3(448, 4), 256, 0, stream>>>(x1, zA, 1024, gcoff, gcsrc, gccoef);
    kgemm<<<dim3(16, 7, 8), 256, 0, stream>>>(zA, W5, part, 1024, 1024, 128);
    kredE<4, true><<<400, 256, 0, stream>>>(part, 8, b5, bn5s, bn5t, nullptr,
                                            lng, lnb, codet, nullptr);
    // ---- decoder ----
    kwd1<<<512, 256, 0, stream>>>(Wd1, codet, dpart);
    kredA<<<dim3(4, 4, 8), 256, 0, stream>>>(dpart, dpart2);
    kred<<<8, 1024, 0, stream>>>(dpart2, 4, 1024, bd1, lnd1g, lnd1b, h1t);
    kwdS<<<64, 128, 0, stream>>>(Wd2, h1t, dpart, 512, 16);
    kred<<<8, 512, 0, stream>>>(dpart, 64, 512, bd2, lnd2g, lnd2b, h2t);
    kwdS<<<32, 64, 0, stream>>>(Wd3, h2t, dpart, 256, 16);
    kred<<<8, 256, 0, stream>>>(dpart, 32, 256, bd3, lnd3g, lnd3b, h3t);
    kwfc<<<1, 256, 0, stream>>>(Wfc, bfc, h3t, hyp);
    // ---- y update + output ----
    kyupd<<<1600, 256, 0, stream>>>(atay, atb, yb, Ub, db, hyp, sumnb,
                                    out + (size_t)k * 409600, mgs[k], mvs[k], k == 0);
    kdeltaU<<<dim3(4, 50, 8), 256, 0, stream>>>(yb, db, Ub, hyp, nbroff, nbridx, mvs[k], k == 0);
  }
}